// Round 3
// baseline (608.846 us; speedup 1.0000x reference)
//
#include <hip/hip_runtime.h>
#include <math.h>

#define K_DIM 2048
#define M_DIM 512
#define N_DIM 64
#define EPSF 1e-8f

typedef float f32x4 __attribute__((ext_vector_type(4)));

// ---------------------------------------------------------------------------
// Kernel A: per-column n, thr = L-th largest of w_b[:,n]; write scores_hard.
// thr = min{ v in column : count(column > v) <= L-1 }  (duplicate-safe)
// ---------------------------------------------------------------------------
__global__ __launch_bounds__(256) void thr_hard_kernel(
    const float* __restrict__ w_b, const int* __restrict__ lptr,
    float* __restrict__ scores_hard) {
  __shared__ float col[M_DIM];
  __shared__ float red[256];
  const int n = blockIdx.x;   // 0..N-1
  const int t = threadIdx.x;  // 0..255
  const int L = lptr[0];

  col[t]       = w_b[t * N_DIM + n];
  col[t + 256] = w_b[(t + 256) * N_DIM + n];
  __syncthreads();

  const float v0 = col[t], v1 = col[t + 256];
  int c0 = 0, c1 = 0;
  for (int i = 0; i < M_DIM; ++i) {
    const float c = col[i];  // broadcast read, conflict-free
    c0 += (c > v0);
    c1 += (c > v1);
  }
  float cand0 = (c0 <= L - 1) ? v0 : INFINITY;
  float cand1 = (c1 <= L - 1) ? v1 : INFINITY;
  red[t] = fminf(cand0, cand1);
  __syncthreads();
  for (int s = 128; s > 0; s >>= 1) {
    if (t < s) red[t] = fminf(red[t], red[t + s]);
    __syncthreads();
  }
  const float thr = red[0];

  // scores_hard[m][n] = (clip(w_b - thr + EPS, -1, 1) + 1) * 0.5
  {
    float sh0 = (col[t] - thr) + EPSF;
    float sh1 = (col[t + 256] - thr) + EPSF;
    sh0 = fminf(fmaxf(sh0, -1.0f), 1.0f);
    sh1 = fminf(fmaxf(sh1, -1.0f), 1.0f);
    scores_hard[t * N_DIM + n]         = (sh0 + 1.0f) * 0.5f;
    scores_hard[(t + 256) * N_DIM + n] = (sh1 + 1.0f) * 0.5f;
  }
}

// ---------------------------------------------------------------------------
// Kernel B: S = x @ w_att   ([K,M] @ [M,M] -> [K,M]), fp32 vector ALU.
// 8 rows per block, x-tile in LDS, 2 output columns per thread.
// ---------------------------------------------------------------------------
__global__ __launch_bounds__(256) void gemm_kernel(
    const float* __restrict__ x, const float* __restrict__ w,
    float* __restrict__ S) {
  __shared__ float xs[8][M_DIM];  // 16 KiB
  const int t = threadIdx.x;
  const int k0 = blockIdx.x * 8;

#pragma unroll
  for (int i = 0; i < 16; ++i) {
    const int idx = i * 256 + t;
    const int r = idx >> 9, c = idx & (M_DIM - 1);
    xs[r][c] = x[(k0 + r) * M_DIM + c];
  }
  __syncthreads();

  float acc0[8], acc1[8];
#pragma unroll
  for (int r = 0; r < 8; ++r) { acc0[r] = 0.0f; acc1[r] = 0.0f; }

  const int j0 = t, j1 = t + 256;
  for (int m = 0; m < M_DIM; m += 4) {
    const float w00 = w[(m + 0) * M_DIM + j0];
    const float w01 = w[(m + 1) * M_DIM + j0];
    const float w02 = w[(m + 2) * M_DIM + j0];
    const float w03 = w[(m + 3) * M_DIM + j0];
    const float w10 = w[(m + 0) * M_DIM + j1];
    const float w11 = w[(m + 1) * M_DIM + j1];
    const float w12 = w[(m + 2) * M_DIM + j1];
    const float w13 = w[(m + 3) * M_DIM + j1];
#pragma unroll
    for (int r = 0; r < 8; ++r) {
      const float4 xv = *(const float4*)&xs[r][m];  // broadcast b128 read
      acc0[r] += xv.x * w00 + xv.y * w01 + xv.z * w02 + xv.w * w03;
      acc1[r] += xv.x * w10 + xv.y * w11 + xv.z * w12 + xv.w * w13;
    }
  }

#pragma unroll
  for (int r = 0; r < 8; ++r) {
    S[(k0 + r) * M_DIM + j0] = acc0[r];
    S[(k0 + r) * M_DIM + j1] = acc1[r];
  }
}

// ---------------------------------------------------------------------------
// Kernel C: in-place row softmax over M_DIM, +EPS. One block per row.
// ---------------------------------------------------------------------------
__global__ __launch_bounds__(256) void softmax_kernel(float* __restrict__ S) {
  __shared__ float red[256];
  const int row = blockIdx.x, t = threadIdx.x;
  const float s0 = S[row * M_DIM + t];
  const float s1 = S[row * M_DIM + t + 256];

  red[t] = fmaxf(s0, s1);
  __syncthreads();
  for (int s = 128; s > 0; s >>= 1) {
    if (t < s) red[t] = fmaxf(red[t], red[t + s]);
    __syncthreads();
  }
  const float mx = red[0];
  __syncthreads();

  const float e0 = expf(s0 - mx);
  const float e1 = expf(s1 - mx);
  red[t] = e0 + e1;
  __syncthreads();
  for (int s = 128; s > 0; s >>= 1) {
    if (t < s) red[t] += red[t + s];
    __syncthreads();
  }
  const float inv = 1.0f / red[0];
  S[row * M_DIM + t]       = e0 * inv + EPSF;
  S[row * M_DIM + t + 256] = e1 * inv + EPSF;
}

// ---------------------------------------------------------------------------
// Kernel D: out[k,m,n] and mask_weight[k,m,n]. Write-bound (512 MiB).
// gid = pair*16 + q; pair = k*M+m; q indexes the float4 within the n-row.
// float4 index into out/mw is exactly gid -> perfectly coalesced stores.
// ---------------------------------------------------------------------------
__global__ __launch_bounds__(256) void combine_kernel(
    const float* __restrict__ x, const float* __restrict__ hard,
    const float* __restrict__ soft, f32x4* __restrict__ out,
    f32x4* __restrict__ mw) {
  const int gid = blockIdx.x * 256 + threadIdx.x;
  const int pair = gid >> 4;       // k*M + m
  const int q = gid & 15;          // float4 index within n-row
  const int m = pair & (M_DIM - 1);

  const float ss = soft[pair];     // broadcast across 16 lanes
  const float xv = x[pair];
  const f32x4 sh = *(const f32x4*)&hard[m * N_DIM + q * 4];

  f32x4 w = sh * ss;
  f32x4 o = w * xv;

  __builtin_nontemporal_store(o, &out[gid]);
  __builtin_nontemporal_store(w, &mw[gid]);
}

// ---------------------------------------------------------------------------
extern "C" void kernel_launch(void* const* d_in, const int* in_sizes, int n_in,
                              void* d_out, int out_size, void* d_ws,
                              size_t ws_size, hipStream_t stream) {
  const float* x     = (const float*)d_in[0];
  const float* w_att = (const float*)d_in[1];
  const float* w_b   = (const float*)d_in[2];
  const int*   lptr  = (const int*)d_in[3];

  float* out_base = (float*)d_out;
  const size_t OUT_SZ = (size_t)K_DIM * M_DIM * N_DIM;  // 67,108,864
  float* out0 = out_base;                               // out [K,M,N]
  float* hard = out0 + OUT_SZ;                          // scores_hard [M,N]
  float* soft = hard + (size_t)M_DIM * N_DIM;           // scores_soft [K,M]
  float* mwp  = soft + (size_t)K_DIM * M_DIM;           // mask_weight [K,M,N]

  thr_hard_kernel<<<N_DIM, 256, 0, stream>>>(w_b, lptr, hard);
  gemm_kernel<<<K_DIM / 8, 256, 0, stream>>>(x, w_att, soft);
  softmax_kernel<<<K_DIM, 256, 0, stream>>>(soft);

  const int total4 = K_DIM * M_DIM * 16;  // one thread per float4
  combine_kernel<<<total4 / 256, 256, 0, stream>>>(
      x, hard, soft, (f32x4*)out0, (f32x4*)mwp);
}